// Round 1
// 875.346 us; speedup vs baseline: 1.0178x; 1.0178x over previous
//
#include <hip/hip_runtime.h>
#include <math.h>

constexpr int NB = 32;    // batch
constexpr int NM = 20;    // modes
constexpr int NP = 8;     // points per mode (== EGO_FUT_TS)
constexpr int ND = 256;   // model dim
constexpr int NA = 32;    // agents
constexpr int NFF = 1024; // ffn dim
constexpr int NH = 128, NW = 128;
constexpr int HW = NH * NW;

// packed bf16 weight region offsets (in bf16 elements) inside d_ws
constexpr int PK_BVW = 0;
constexpr int PK_BOW = 65536;
constexpr int PK_WQ  = 131072;
constexpr int PK_WO  = 196608;
constexpr int PK_CW1 = 262144;
constexpr int PK_CW2 = 327680;
constexpr int PK_RW1 = 393216;
constexpr int PK_RW2 = 458752;
// (gap 524288..655359 where WK/WV used to live — kv now reads fp32 directly)
constexpr int PK_FW1 = 655360;
constexpr int PK_FW2 = 917504;
constexpr int PK_ELEMS = 1048576;   // elements actually packed (10 segments)

// float-offsets in workspace (unchanged layout)
constexpr int WS_GW   = 0;              // 640*256
constexpr int WS_WSUM = 163840;         // 640
constexpr int WS_K1   = 164480;         // 1024*256
constexpr int WS_V1   = 426624;         // 1024*256
constexpr int WS_U    = 688768;         // 32*256
constexpr int WS_SS   = 696960;         // 32*512
constexpr int WS_PACK = 720896;         // bf16 area starts here (8B aligned)

// ---------------------------------------------------------------------------
// decode 2 bf16 (halfwords of u) to fp32
__device__ __forceinline__ void dec2(unsigned u, float& f0, float& f1) {
    union { unsigned x; float f; } a, b;
    a.x = u << 16;
    b.x = u & 0xffff0000u;
    f0 = a.f; f1 = b.f;
}

__device__ __forceinline__ float fma4(float4 a, uint2 w, float acc) {
    float w0, w1, w2, w3;
    dec2(w.x, w0, w1);
    dec2(w.y, w2, w3);
    acc += a.x * w0;
    acc += a.y * w1;
    acc += a.z * w2;
    acc += a.w * w3;
    return acc;
}

// GEMM col for K=256, N=256: acc += sum_c sa[c] * W[c][t]
__device__ __forceinline__ float gemm256(const uint2* __restrict__ wp, const float* __restrict__ sa,
                                         int t, float acc) {
    const float4* a4 = (const float4*)sa;
    #pragma unroll 8
    for (int c4 = 0; c4 < 64; ++c4) {
        float4 a = a4[c4];
        uint2 w = wp[(c4 << 8) + t];
        acc = fma4(a, w, acc);
    }
    return acc;
}

// ---------------------------------------------------------------------------
// Fused prologue: grid segments [gather | kv | perb | pack]
constexpr int GB_GATHER = NB * NM;         // 640
constexpr int GB_KV     = NB * NA / 4;     // 256 (4 agents/block -> same weight traffic as packed)
constexpr int GB_PERB   = NB;              // 32
constexpr int GB_PACK   = PK_ELEMS / 256;  // 4096
constexpr int PRO_GRID  = GB_GATHER + GB_KV + GB_PERB + GB_PACK;

struct PackArgs {
    const float* src[10];
    int log2N[10];
    int elems[10];
    int dstoff[10];
};

struct ProArgs {
    const float *traj, *noisy, *bev, *attn_w, *attn_b;
    const float *agents, *wk, *bk, *wv, *bv;
    const float *ego, *eq_wv, *eq_bv, *eq_wo, *eq_bo;
    const float *temb, *modw, *modb;
    float *gw, *wsum, *K1, *V1, *u, *ss;
    unsigned short* pk;
};

__global__ void prologue_kernel(ProArgs A, PackArgs pa) {
    int blk = blockIdx.x, tid = threadIdx.x;
    __shared__ __align__(16) float sm0[ND];
    __shared__ __align__(16) float sm1[ND];
    __shared__ __align__(16) float sm2[ND];
    __shared__ __align__(16) float sm3[ND];
    __shared__ float s_ptw[NP];
    __shared__ float s_w[32];
    __shared__ int s_idx[32];

    if (blk < GB_GATHER) {
        // ---------------- point-softmax + bilinear gather ----------------
        int b = blk / NM;
        sm0[tid] = A.traj[(size_t)blk * ND + tid];
        __syncthreads();
        if (tid < NP) {
            float acc = A.attn_b[tid];
            for (int c = 0; c < ND; c++) acc += sm0[c] * A.attn_w[c * NP + tid];
            s_ptw[tid] = acc;
        }
        __syncthreads();
        if (tid == 0) {
            float mx = s_ptw[0];
            for (int p = 1; p < NP; p++) mx = fmaxf(mx, s_ptw[p]);
            float e[NP], sum = 0.f;
            for (int p = 0; p < NP; p++) { e[p] = expf(s_ptw[p] - mx); sum += e[p]; }
            for (int p = 0; p < NP; p++) s_ptw[p] = e[p] / sum;
        }
        __syncthreads();
        if (tid < 32) {
            int p = tid >> 2, corner = tid & 3;
            float gx = A.noisy[((size_t)blk * NP + p) * 2 + 0] * (1.0f / 32.0f);
            float gy = A.noisy[((size_t)blk * NP + p) * 2 + 1] * (1.0f / 32.0f);
            float x = (gx + 1.0f) * (NW * 0.5f) - 0.5f;
            float y = (gy + 1.0f) * (NH * 0.5f) - 0.5f;
            float x0 = floorf(x), y0 = floorf(y);
            int dx = corner & 1, dy = corner >> 1;
            float wx = dx ? (x - x0) : (x0 + 1.0f - x);
            float wy = dy ? (y - y0) : (y0 + 1.0f - y);
            float xi = x0 + (float)dx, yi = y0 + (float)dy;
            bool valid = (xi >= 0.f) && (xi <= (float)(NW - 1)) && (yi >= 0.f) && (yi <= (float)(NH - 1));
            int xc = (int)fminf(fmaxf(xi, 0.f), (float)(NW - 1));
            int yc = (int)fminf(fmaxf(yi, 0.f), (float)(NH - 1));
            s_w[tid] = wx * wy * (valid ? 1.f : 0.f) * s_ptw[p];
            s_idx[tid] = yc * NW + xc;
        }
        __syncthreads();
        if (tid == 0) {
            float s = 0.f;
            for (int j = 0; j < 32; j++) s += s_w[j];
            A.wsum[blk] = s;
        }
        const float* base = A.bev + (size_t)b * ND * HW + (size_t)tid * HW;
        float acc0 = 0.f, acc1 = 0.f;
        #pragma unroll
        for (int j = 0; j < 32; j += 2) {
            acc0 += s_w[j]     * base[s_idx[j]];
            acc1 += s_w[j + 1] * base[s_idx[j + 1]];
        }
        A.gw[(size_t)blk * ND + tid] = acc0 + acc1;
    } else if (blk < GB_GATHER + GB_KV) {
        // ---------------- agents K/V projection, 4 agents/block, fp32 W ----
        int a0 = (blk - GB_GATHER) * 4;
        sm0[tid] = A.agents[(size_t)a0 * ND + tid];
        sm1[tid] = A.agents[(size_t)(a0 + 1) * ND + tid];
        sm2[tid] = A.agents[(size_t)(a0 + 2) * ND + tid];
        sm3[tid] = A.agents[(size_t)(a0 + 3) * ND + tid];
        __syncthreads();
        float k0 = A.bk[tid], k1 = k0, k2 = k0, k3 = k0;
        float v0 = A.bv[tid], v1 = v0, v2 = v0, v3 = v0;
        #pragma unroll 4
        for (int c = 0; c < ND; ++c) {
            float wk = A.wk[(size_t)c * ND + tid];
            float wv = A.wv[(size_t)c * ND + tid];
            float a0f = sm0[c], a1f = sm1[c], a2f = sm2[c], a3f = sm3[c];
            k0 += a0f * wk; k1 += a1f * wk; k2 += a2f * wk; k3 += a3f * wk;
            v0 += a0f * wv; v1 += a1f * wv; v2 += a2f * wv; v3 += a3f * wv;
        }
        A.K1[(size_t)a0 * ND + tid] = k0;
        A.K1[(size_t)(a0 + 1) * ND + tid] = k1;
        A.K1[(size_t)(a0 + 2) * ND + tid] = k2;
        A.K1[(size_t)(a0 + 3) * ND + tid] = k3;
        A.V1[(size_t)a0 * ND + tid] = v0;
        A.V1[(size_t)(a0 + 1) * ND + tid] = v1;
        A.V1[(size_t)(a0 + 2) * ND + tid] = v2;
        A.V1[(size_t)(a0 + 3) * ND + tid] = v3;
    } else if (blk < GB_GATHER + GB_KV + GB_PERB) {
        // ---------------- per-batch ego collapse + modulation --------------
        int b = blk - (GB_GATHER + GB_KV);
        sm0[tid] = A.ego[(size_t)b * ND + tid];
        __syncthreads();
        float v = A.eq_bv[tid];
        for (int c = 0; c < ND; c++) v += sm0[c] * A.eq_wv[c * ND + tid];
        sm1[tid] = v;
        __syncthreads();
        float o = A.eq_bo[tid];
        for (int c = 0; c < ND; c++) o += sm1[c] * A.eq_wo[c * ND + tid];
        A.u[(size_t)b * ND + tid] = o;

        float te = A.temb[(size_t)b * ND + tid];
        float sp = log1pf(expf(te));          // softplus
        float me = te * tanhf(sp);            // mish
        __syncthreads();
        sm0[tid] = me;
        __syncthreads();
        for (int jj = 0; jj < 2; jj++) {
            int j = tid + jj * ND;
            float acc = A.modb[j];
            for (int c = 0; c < ND; c++) acc += sm0[c] * A.modw[(size_t)c * 2 * ND + j];
            A.ss[(size_t)b * 2 * ND + j] = acc;
        }
    } else {
        // ---------------- pack fp32 weights -> bf16 [K/4][N][4] ------------
        int e = (blk - (GB_GATHER + GB_KV + GB_PERB)) * 256 + tid;
        int seg = 0;
        while (seg < 10 && e >= pa.elems[seg]) { e -= pa.elems[seg]; seg++; }
        if (seg < 10) {
            int lg = pa.log2N[seg];
            int N = 1 << lg;
            int c = e >> lg;
            int n = e & (N - 1);
            float v = pa.src[seg][e];
            union { float f; unsigned u; } uu; uu.f = v;
            unsigned x = uu.u;
            unsigned r = (x + 0x7fff + ((x >> 16) & 1)) >> 16;  // bf16 RNE
            int idx = (((c >> 2) << lg) + n) * 4 + (c & 3);
            A.pk[pa.dstoff[seg] + idx] = (unsigned short)r;
        }
    }
}

// ---------------------------------------------------------------------------
// per-half (256-thread) reductions inside a 512-thread block.
// waves 0-3 = half 0, waves 4-7 = half 1.
__device__ __forceinline__ float half_sum(float v, float* s_red, int tid) {
    for (int off = 32; off > 0; off >>= 1) v += __shfl_down(v, off, 64);
    __syncthreads();
    if ((tid & 63) == 0) s_red[tid >> 6] = v;
    __syncthreads();
    int base = (tid >> 8) << 2;
    return s_red[base] + s_red[base + 1] + s_red[base + 2] + s_red[base + 3];
}

__device__ __forceinline__ float half_ln(float x, const float* g, const float* bb, float* s_red, int tid) {
    int t = tid & 255;
    float mean = half_sum(x, s_red, tid) * (1.0f / 256.0f);
    float xm = x - mean;
    float var = half_sum(xm * xm, s_red, tid) * (1.0f / 256.0f);
    return xm / sqrtf(var + 1e-5f) * g[t] + bb[t];
}

// ---------------------------------------------------------------------------
// Megakernel: one block per TOKEN PAIR (512 threads; half = token).
// Both halves issue identical weight/K1/V1 address streams -> weight L2
// traffic halves vs. one-token blocks; wave count unchanged (320x8 = 2560).
struct MegaW {
    const float *traj, *noisy;
    const float *bvb, *bob, *bq, *bo;
    const float *n1g, *n1b, *n2g, *n2b;
    const float *fb1, *fb2, *n3g, *n3b;
    const float *cb1, *cl1g, *cl1b, *cb2, *cl2g, *cl2b, *cw3, *cb3;
    const float *rb1, *rb2, *rw3, *rb3;
};

__global__ __launch_bounds__(512, 4)
void mega_kernel(const float* __restrict__ gw, const float* __restrict__ wsumw,
                 const float* __restrict__ K1, const float* __restrict__ V1,
                 const float* __restrict__ u, const float* __restrict__ ss,
                 const uint2* __restrict__ bvwp, const uint2* __restrict__ bowp,
                 const uint2* __restrict__ wqp, const uint2* __restrict__ wop,
                 const uint2* __restrict__ fw1p, const uint2* __restrict__ fw2p,
                 const uint2* __restrict__ cw1p, const uint2* __restrict__ cw2p,
                 const uint2* __restrict__ rw1p, const uint2* __restrict__ rw2p,
                 MegaW W, float* __restrict__ out) {
    int blk = blockIdx.x;
    int tid = threadIdx.x;
    int half = tid >> 8;
    int t = tid & 255;
    int tok = blk * 2 + half;          // NM=20 even -> pair never crosses batch
    int b = tok / NM;
    __shared__ __align__(16) float s_a[2][ND];
    __shared__ __align__(16) float s_b[2][ND];
    __shared__ __align__(16) float s_h[2][NFF];
    __shared__ __align__(16) float s_sc[2][ND];
    __shared__ float s_red[8];

    // --- bev value GEMM: sampled' = gw @ W_v + b_v * wsum
    s_sc[half][t] = gw[(size_t)tok * ND + t];
    float wsw = wsumw[tok];
    __syncthreads();
    float acc = gemm256(bvwp, s_sc[half], t, W.bvb[t] * wsw);
    __syncthreads();
    s_b[half][t] = acc;
    __syncthreads();
    // --- bev out GEMM + residual with traj_feature -> t0 in s_a
    acc = gemm256(bowp, s_b[half], t, W.bob[t] + W.traj[(size_t)tok * ND + t]);
    s_a[half][t] = acc;
    __syncthreads();
    // --- agents attention: q projection
    acc = gemm256(wqp, s_a[half], t, W.bq[t]);
    __syncthreads();
    s_b[half][t] = acc;   // q
    __syncthreads();
    int h = t >> 5, kk = t & 31;
    {
        const float* Krow = K1 + ((size_t)(b * NA + kk)) * ND + h * 32;
        float sc = 0.f;
        for (int j = 0; j < 32; j++) sc += s_b[half][h * 32 + j] * Krow[j];
        s_sc[half][t] = sc * 0.17677669529663687f;   // 1/sqrt(32)
    }
    __syncthreads();
    // softmax over the 32 keys of this head
    {
        float mx = -1e30f;
        for (int j = 0; j < 32; j++) mx = fmaxf(mx, s_sc[half][h * 32 + j]);
        float den = 0.f;
        for (int j = 0; j < 32; j++) den += expf(s_sc[half][h * 32 + j] - mx);
        float p = expf(s_sc[half][t] - mx) / den;
        __syncthreads();
        s_sc[half][t] = p;
        __syncthreads();
    }
    // attn out
    {
        const float* Vb = V1 + (size_t)b * NA * ND;
        float o = 0.f;
        for (int k = 0; k < 32; k++) o += s_sc[half][h * 32 + k] * Vb[(size_t)k * ND + t];
        __syncthreads();
        s_b[half][t] = o;
        __syncthreads();
    }
    // output proj + residual + LN1
    acc = gemm256(wop, s_b[half], t, W.bo[t] + s_a[half][t]);
    float t1 = half_ln(acc, W.n1g, W.n1b, s_red, tid);
    // ego (collapsed) residual + LN2
    float t2 = half_ln(t1 + u[(size_t)b * ND + t], W.n2g, W.n2b, s_red, tid);
    __syncthreads();
    s_a[half][t] = t2;
    __syncthreads();
    // --- FFN1: h = relu(t2 @ fw1 + fb1)  (K=256, N=1024, 4 outs/thread)
    {
        float f0 = W.fb1[t], f1 = W.fb1[t + 256], f2 = W.fb1[t + 512], f3 = W.fb1[t + 768];
        const float4* a4 = (const float4*)s_a[half];
        #pragma unroll 4
        for (int c4 = 0; c4 < 64; ++c4) {
            float4 a = a4[c4];
            f0 = fma4(a, fw1p[(c4 << 10) + t], f0);
            f1 = fma4(a, fw1p[(c4 << 10) + 256 + t], f1);
            f2 = fma4(a, fw1p[(c4 << 10) + 512 + t], f2);
            f3 = fma4(a, fw1p[(c4 << 10) + 768 + t], f3);
        }
        s_h[half][t] = fmaxf(f0, 0.f);
        s_h[half][t + 256] = fmaxf(f1, 0.f);
        s_h[half][t + 512] = fmaxf(f2, 0.f);
        s_h[half][t + 768] = fmaxf(f3, 0.f);
    }
    __syncthreads();
    // --- FFN2 (K=1024)
    {
        acc = W.fb2[t];
        const float4* h4 = (const float4*)s_h[half];
        #pragma unroll 8
        for (int c4 = 0; c4 < 256; ++c4) {
            acc = fma4(h4[c4], fw2p[(c4 << 8) + t], acc);
        }
    }
    float t3 = half_ln(acc, W.n3g, W.n3b, s_red, tid);   // no residual, per reference
    // modulation
    float sc1 = ss[(size_t)b * 2 * ND + t];
    float sh1 = ss[(size_t)b * 2 * ND + ND + t];
    float tt = t3 * (1.f + sc1) + sh1;
    __syncthreads();
    s_a[half][t] = tt;
    __syncthreads();
    // --- cls head
    acc = gemm256(cw1p, s_a[half], t, W.cb1[t]);
    float h1 = half_ln(fmaxf(acc, 0.f), W.cl1g, W.cl1b, s_red, tid);
    __syncthreads();
    s_b[half][t] = h1;
    __syncthreads();
    acc = gemm256(cw2p, s_b[half], t, W.cb2[t]);
    float h2 = half_ln(fmaxf(acc, 0.f), W.cl2g, W.cl2b, s_red, tid);
    float pc = half_sum(h2 * W.cw3[t], s_red, tid);
    if (t == 0) out[(size_t)NB * NM * NP * 3 + tok] = pc + W.cb3[0];
    // --- reg head
    acc = gemm256(rw1p, s_a[half], t, W.rb1[t]);
    __syncthreads();
    s_b[half][t] = fmaxf(acc, 0.f);
    __syncthreads();
    acc = gemm256(rw2p, s_b[half], t, W.rb2[t]);
    __syncthreads();
    s_b[half][t] = fmaxf(acc, 0.f);
    __syncthreads();
    if (t < 24) {
        float r3 = W.rb3[t];
        for (int c = 0; c < ND; c++) r3 += s_b[half][c] * W.rw3[c * 24 + t];
        int ts = t / 3, k2 = t % 3;
        float val;
        if (k2 < 2) val = r3 + W.noisy[((size_t)tok * NP + ts) * 2 + k2];
        else        val = tanhf(r3) * 3.14159265358979323846f;
        out[((size_t)tok * NP + ts) * 3 + k2] = val;
    }
}

// ---------------------------------------------------------------------------
extern "C" void kernel_launch(void* const* d_in, const int* in_sizes, int n_in,
                              void* d_out, int out_size, void* d_ws, size_t ws_size,
                              hipStream_t stream) {
    const float* traj   = (const float*)d_in[0];
    const float* noisy  = (const float*)d_in[1];
    const float* bev    = (const float*)d_in[2];
    const float* agents = (const float*)d_in[3];
    const float* ego    = (const float*)d_in[4];
    const float* temb   = (const float*)d_in[5];
    const float* bvw = (const float*)d_in[7];
    const float* bvb = (const float*)d_in[8];
    const float* baw = (const float*)d_in[9];
    const float* bab = (const float*)d_in[10];
    const float* bow = (const float*)d_in[11];
    const float* bob = (const float*)d_in[12];
    const float* aq_wq = (const float*)d_in[13];
    const float* aq_bq = (const float*)d_in[14];
    const float* aq_wk = (const float*)d_in[15];
    const float* aq_bk = (const float*)d_in[16];
    const float* aq_wv = (const float*)d_in[17];
    const float* aq_bv = (const float*)d_in[18];
    const float* aq_wo = (const float*)d_in[19];
    const float* aq_bo = (const float*)d_in[20];
    // 21..24: eq_wq/bq/wk/bk dead (Lk==1 -> softmax==1)
    const float* eq_wv = (const float*)d_in[25];
    const float* eq_bv = (const float*)d_in[26];
    const float* eq_wo = (const float*)d_in[27];
    const float* eq_bo = (const float*)d_in[28];
    const float* fw1 = (const float*)d_in[29];
    const float* fb1 = (const float*)d_in[30];
    const float* fw2 = (const float*)d_in[31];
    const float* fb2 = (const float*)d_in[32];
    const float* n1g = (const float*)d_in[33];
    const float* n1b = (const float*)d_in[34];
    const float* n2g = (const float*)d_in[35];
    const float* n2b = (const float*)d_in[36];
    const float* n3g = (const float*)d_in[37];
    const float* n3b = (const float*)d_in[38];
    const float* modw = (const float*)d_in[39];
    const float* modb = (const float*)d_in[40];
    const float* cw1 = (const float*)d_in[41];
    const float* cb1 = (const float*)d_in[42];
    const float* cl1g = (const float*)d_in[43];
    const float* cl1b = (const float*)d_in[44];
    const float* cw2 = (const float*)d_in[45];
    const float* cb2 = (const float*)d_in[46];
    const float* cl2g = (const float*)d_in[47];
    const float* cl2b = (const float*)d_in[48];
    const float* cw3 = (const float*)d_in[49];
    const float* cb3 = (const float*)d_in[50];
    const float* rw1 = (const float*)d_in[51];
    const float* rb1 = (const float*)d_in[52];
    const float* rw2 = (const float*)d_in[53];
    const float* rb2 = (const float*)d_in[54];
    const float* rw3 = (const float*)d_in[55];
    const float* rb3 = (const float*)d_in[56];

    float* ws = (float*)d_ws;
    float* gw    = ws + WS_GW;
    float* wsumw = ws + WS_WSUM;
    float* K1    = ws + WS_K1;
    float* V1    = ws + WS_V1;
    float* u     = ws + WS_U;
    float* ssb   = ws + WS_SS;
    unsigned short* pk = (unsigned short*)(ws + WS_PACK);

    // ---- fused prologue: pack + gather + kv + perb in one dispatch
    PackArgs pa;
    const float* srcs[10] = {bvw, bow, aq_wq, aq_wo, cw1, cw2, rw1, rw2, fw1, fw2};
    int lg[10]  = {8, 8, 8, 8, 8, 8, 8, 8, 10, 8};
    int el[10]  = {65536, 65536, 65536, 65536, 65536, 65536, 65536, 65536, 262144, 262144};
    int off[10] = {PK_BVW, PK_BOW, PK_WQ, PK_WO, PK_CW1, PK_CW2, PK_RW1, PK_RW2, PK_FW1, PK_FW2};
    for (int i = 0; i < 10; i++) { pa.src[i] = srcs[i]; pa.log2N[i] = lg[i]; pa.elems[i] = el[i]; pa.dstoff[i] = off[i]; }

    ProArgs PA;
    PA.traj = traj; PA.noisy = noisy; PA.bev = bev; PA.attn_w = baw; PA.attn_b = bab;
    PA.agents = agents; PA.wk = aq_wk; PA.bk = aq_bk; PA.wv = aq_wv; PA.bv = aq_bv;
    PA.ego = ego; PA.eq_wv = eq_wv; PA.eq_bv = eq_bv; PA.eq_wo = eq_wo; PA.eq_bo = eq_bo;
    PA.temb = temb; PA.modw = modw; PA.modb = modb;
    PA.gw = gw; PA.wsum = wsumw; PA.K1 = K1; PA.V1 = V1; PA.u = u; PA.ss = ssb;
    PA.pk = pk;

    prologue_kernel<<<dim3(PRO_GRID), dim3(256), 0, stream>>>(PA, pa);

    MegaW W;
    W.traj = traj; W.noisy = noisy;
    W.bvb = bvb; W.bob = bob; W.bq = aq_bq; W.bo = aq_bo;
    W.n1g = n1g; W.n1b = n1b; W.n2g = n2g; W.n2b = n2b;
    W.fb1 = fb1; W.fb2 = fb2; W.n3g = n3g; W.n3b = n3b;
    W.cb1 = cb1; W.cl1g = cl1g; W.cl1b = cl1b;
    W.cb2 = cb2; W.cl2g = cl2g; W.cl2b = cl2b; W.cw3 = cw3; W.cb3 = cb3;
    W.rb1 = rb1; W.rb2 = rb2; W.rw3 = rw3; W.rb3 = rb3;

    mega_kernel<<<dim3(NB * NM / 2), dim3(512), 0, stream>>>(gw, wsumw, K1, V1, u, ssb,
        (const uint2*)(pk + PK_BVW), (const uint2*)(pk + PK_BOW),
        (const uint2*)(pk + PK_WQ),  (const uint2*)(pk + PK_WO),
        (const uint2*)(pk + PK_FW1), (const uint2*)(pk + PK_FW2),
        (const uint2*)(pk + PK_CW1), (const uint2*)(pk + PK_CW2),
        (const uint2*)(pk + PK_RW1), (const uint2*)(pk + PK_RW2),
        W, (float*)d_out);
}

// Round 2
// 831.633 us; speedup vs baseline: 1.0713x; 1.0526x over previous
//
#include <hip/hip_runtime.h>
#include <math.h>

constexpr int NB = 32;    // batch
constexpr int NM = 20;    // modes
constexpr int NP = 8;     // points per mode (== EGO_FUT_TS)
constexpr int ND = 256;   // model dim
constexpr int NA = 32;    // agents
constexpr int NFF = 1024; // ffn dim
constexpr int NH = 128, NW = 128;
constexpr int HW = NH * NW;

// packed bf16 weight region offsets (in bf16 elements) inside d_ws
constexpr int PK_BVW = 0;
constexpr int PK_BOW = 65536;
constexpr int PK_WQ  = 131072;
constexpr int PK_WO  = 196608;
constexpr int PK_CW1 = 262144;
constexpr int PK_CW2 = 327680;
constexpr int PK_RW1 = 393216;
constexpr int PK_RW2 = 458752;
constexpr int PK_FW1 = 655360;
constexpr int PK_FW2 = 917504;
constexpr int PK_ELEMS = 1048576;   // elements actually packed (10 segments)

// float-offsets in workspace (unchanged layout)
constexpr int WS_GW   = 0;              // 640*256
constexpr int WS_WSUM = 163840;         // 640
constexpr int WS_K1   = 164480;         // 1024*256
constexpr int WS_V1   = 426624;         // 1024*256
constexpr int WS_U    = 688768;         // 32*256
constexpr int WS_SS   = 696960;         // 32*512
constexpr int WS_PACK = 720896;         // bf16 area starts here (8B aligned)

// ---------------------------------------------------------------------------
// decode 2 bf16 (halfwords of u) to fp32
__device__ __forceinline__ void dec2(unsigned u, float& f0, float& f1) {
    union { unsigned x; float f; } a, b;
    a.x = u << 16;
    b.x = u & 0xffff0000u;
    f0 = a.f; f1 = b.f;
}

// dual-token fma: acc.{x,y} += a.{x,y} * w   (maps to v_pk_fma_f32)
__device__ __forceinline__ float2 pk_fma(float2 a, float w, float2 acc) {
    acc.x = fmaf(a.x, w, acc.x);
    acc.y = fmaf(a.y, w, acc.y);
    return acc;
}

// scalar path (prologue kv etc.)
__device__ __forceinline__ float fma4(float4 a, uint2 w, float acc) {
    float w0, w1, w2, w3;
    dec2(w.x, w0, w1);
    dec2(w.y, w2, w3);
    acc += a.x * w0;
    acc += a.y * w1;
    acc += a.z * w2;
    acc += a.w * w3;
    return acc;
}

// dual-token GEMM col for K=256, N=256. sa2 = interleaved (tokA,tokB) pairs.
__device__ __forceinline__ float2 gemm256x2(const uint2* __restrict__ wp, const float2* __restrict__ sa2,
                                            int t, float2 acc) {
    const float4* a4 = (const float4*)sa2;
    #pragma unroll 8
    for (int c4 = 0; c4 < 64; ++c4) {
        float4 p = a4[c4 * 2];
        float4 q = a4[c4 * 2 + 1];
        uint2 w = wp[(c4 << 8) + t];
        float w0, w1, w2, w3;
        dec2(w.x, w0, w1);
        dec2(w.y, w2, w3);
        acc = pk_fma(make_float2(p.x, p.y), w0, acc);
        acc = pk_fma(make_float2(p.z, p.w), w1, acc);
        acc = pk_fma(make_float2(q.x, q.y), w2, acc);
        acc = pk_fma(make_float2(q.z, q.w), w3, acc);
    }
    return acc;
}

// ---------------------------------------------------------------------------
// Fused prologue: grid segments [gather | kv | perb | pack]  (unchanged)
constexpr int GB_GATHER = NB * NM;         // 640
constexpr int GB_KV     = NB * NA / 4;     // 256
constexpr int GB_PERB   = NB;              // 32
constexpr int GB_PACK   = PK_ELEMS / 256;  // 4096
constexpr int PRO_GRID  = GB_GATHER + GB_KV + GB_PERB + GB_PACK;

struct PackArgs {
    const float* src[10];
    int log2N[10];
    int elems[10];
    int dstoff[10];
};

struct ProArgs {
    const float *traj, *noisy, *bev, *attn_w, *attn_b;
    const float *agents, *wk, *bk, *wv, *bv;
    const float *ego, *eq_wv, *eq_bv, *eq_wo, *eq_bo;
    const float *temb, *modw, *modb;
    float *gw, *wsum, *K1, *V1, *u, *ss;
    unsigned short* pk;
};

__global__ void prologue_kernel(ProArgs A, PackArgs pa) {
    int blk = blockIdx.x, tid = threadIdx.x;
    __shared__ __align__(16) float sm0[ND];
    __shared__ __align__(16) float sm1[ND];
    __shared__ __align__(16) float sm2[ND];
    __shared__ __align__(16) float sm3[ND];
    __shared__ float s_ptw[NP];
    __shared__ float s_w[32];
    __shared__ int s_idx[32];

    if (blk < GB_GATHER) {
        // ---------------- point-softmax + bilinear gather ----------------
        int b = blk / NM;
        sm0[tid] = A.traj[(size_t)blk * ND + tid];
        __syncthreads();
        if (tid < NP) {
            float acc = A.attn_b[tid];
            for (int c = 0; c < ND; c++) acc += sm0[c] * A.attn_w[c * NP + tid];
            s_ptw[tid] = acc;
        }
        __syncthreads();
        if (tid == 0) {
            float mx = s_ptw[0];
            for (int p = 1; p < NP; p++) mx = fmaxf(mx, s_ptw[p]);
            float e[NP], sum = 0.f;
            for (int p = 0; p < NP; p++) { e[p] = expf(s_ptw[p] - mx); sum += e[p]; }
            for (int p = 0; p < NP; p++) s_ptw[p] = e[p] / sum;
        }
        __syncthreads();
        if (tid < 32) {
            int p = tid >> 2, corner = tid & 3;
            float gx = A.noisy[((size_t)blk * NP + p) * 2 + 0] * (1.0f / 32.0f);
            float gy = A.noisy[((size_t)blk * NP + p) * 2 + 1] * (1.0f / 32.0f);
            float x = (gx + 1.0f) * (NW * 0.5f) - 0.5f;
            float y = (gy + 1.0f) * (NH * 0.5f) - 0.5f;
            float x0 = floorf(x), y0 = floorf(y);
            int dx = corner & 1, dy = corner >> 1;
            float wx = dx ? (x - x0) : (x0 + 1.0f - x);
            float wy = dy ? (y - y0) : (y0 + 1.0f - y);
            float xi = x0 + (float)dx, yi = y0 + (float)dy;
            bool valid = (xi >= 0.f) && (xi <= (float)(NW - 1)) && (yi >= 0.f) && (yi <= (float)(NH - 1));
            int xc = (int)fminf(fmaxf(xi, 0.f), (float)(NW - 1));
            int yc = (int)fminf(fmaxf(yi, 0.f), (float)(NH - 1));
            s_w[tid] = wx * wy * (valid ? 1.f : 0.f) * s_ptw[p];
            s_idx[tid] = yc * NW + xc;
        }
        __syncthreads();
        if (tid == 0) {
            float s = 0.f;
            for (int j = 0; j < 32; j++) s += s_w[j];
            A.wsum[blk] = s;
        }
        const float* base = A.bev + (size_t)b * ND * HW + (size_t)tid * HW;
        float acc0 = 0.f, acc1 = 0.f;
        #pragma unroll
        for (int j = 0; j < 32; j += 2) {
            acc0 += s_w[j]     * base[s_idx[j]];
            acc1 += s_w[j + 1] * base[s_idx[j + 1]];
        }
        A.gw[(size_t)blk * ND + tid] = acc0 + acc1;
    } else if (blk < GB_GATHER + GB_KV) {
        // ---------------- agents K/V projection, 4 agents/block, fp32 W ----
        int a0 = (blk - GB_GATHER) * 4;
        sm0[tid] = A.agents[(size_t)a0 * ND + tid];
        sm1[tid] = A.agents[(size_t)(a0 + 1) * ND + tid];
        sm2[tid] = A.agents[(size_t)(a0 + 2) * ND + tid];
        sm3[tid] = A.agents[(size_t)(a0 + 3) * ND + tid];
        __syncthreads();
        float k0 = A.bk[tid], k1 = k0, k2 = k0, k3 = k0;
        float v0 = A.bv[tid], v1 = v0, v2 = v0, v3 = v0;
        #pragma unroll 4
        for (int c = 0; c < ND; ++c) {
            float wk = A.wk[(size_t)c * ND + tid];
            float wv = A.wv[(size_t)c * ND + tid];
            float a0f = sm0[c], a1f = sm1[c], a2f = sm2[c], a3f = sm3[c];
            k0 += a0f * wk; k1 += a1f * wk; k2 += a2f * wk; k3 += a3f * wk;
            v0 += a0f * wv; v1 += a1f * wv; v2 += a2f * wv; v3 += a3f * wv;
        }
        A.K1[(size_t)a0 * ND + tid] = k0;
        A.K1[(size_t)(a0 + 1) * ND + tid] = k1;
        A.K1[(size_t)(a0 + 2) * ND + tid] = k2;
        A.K1[(size_t)(a0 + 3) * ND + tid] = k3;
        A.V1[(size_t)a0 * ND + tid] = v0;
        A.V1[(size_t)(a0 + 1) * ND + tid] = v1;
        A.V1[(size_t)(a0 + 2) * ND + tid] = v2;
        A.V1[(size_t)(a0 + 3) * ND + tid] = v3;
    } else if (blk < GB_GATHER + GB_KV + GB_PERB) {
        // ---------------- per-batch ego collapse + modulation --------------
        int b = blk - (GB_GATHER + GB_KV);
        sm0[tid] = A.ego[(size_t)b * ND + tid];
        __syncthreads();
        float v = A.eq_bv[tid];
        for (int c = 0; c < ND; c++) v += sm0[c] * A.eq_wv[c * ND + tid];
        sm1[tid] = v;
        __syncthreads();
        float o = A.eq_bo[tid];
        for (int c = 0; c < ND; c++) o += sm1[c] * A.eq_wo[c * ND + tid];
        A.u[(size_t)b * ND + tid] = o;

        float te = A.temb[(size_t)b * ND + tid];
        float sp = log1pf(expf(te));          // softplus
        float me = te * tanhf(sp);            // mish
        __syncthreads();
        sm0[tid] = me;
        __syncthreads();
        for (int jj = 0; jj < 2; jj++) {
            int j = tid + jj * ND;
            float acc = A.modb[j];
            for (int c = 0; c < ND; c++) acc += sm0[c] * A.modw[(size_t)c * 2 * ND + j];
            A.ss[(size_t)b * 2 * ND + j] = acc;
        }
    } else {
        // ---------------- pack fp32 weights -> bf16 [K/4][N][4] ------------
        int e = (blk - (GB_GATHER + GB_KV + GB_PERB)) * 256 + tid;
        int seg = 0;
        while (seg < 10 && e >= pa.elems[seg]) { e -= pa.elems[seg]; seg++; }
        if (seg < 10) {
            int lg = pa.log2N[seg];
            int N = 1 << lg;
            int c = e >> lg;
            int n = e & (N - 1);
            float v = pa.src[seg][e];
            union { float f; unsigned u; } uu; uu.f = v;
            unsigned x = uu.u;
            unsigned r = (x + 0x7fff + ((x >> 16) & 1)) >> 16;  // bf16 RNE
            int idx = (((c >> 2) << lg) + n) * 4 + (c & 3);
            A.pk[pa.dstoff[seg] + idx] = (unsigned short)r;
        }
    }
}

// ---------------------------------------------------------------------------
// per-half (256-thread) dual-token reductions in a 512-thread block.
// waves 0-3 = half 0 (tokens A0,B0), waves 4-7 = half 1 (tokens A1,B1).
__device__ __forceinline__ float2 half_sum2(float2 v, float2* s_red2, int tid) {
    for (int off = 32; off > 0; off >>= 1) {
        v.x += __shfl_down(v.x, off, 64);
        v.y += __shfl_down(v.y, off, 64);
    }
    __syncthreads();
    if ((tid & 63) == 0) s_red2[tid >> 6] = v;
    __syncthreads();
    int base = (tid >> 8) << 2;
    float2 r;
    r.x = s_red2[base].x + s_red2[base + 1].x + s_red2[base + 2].x + s_red2[base + 3].x;
    r.y = s_red2[base].y + s_red2[base + 1].y + s_red2[base + 2].y + s_red2[base + 3].y;
    return r;
}

__device__ __forceinline__ float2 half_ln2(float2 x, const float* g, const float* bb, float2* s_red2, int tid) {
    int t = tid & 255;
    float2 mean = half_sum2(x, s_red2, tid);
    mean.x *= (1.0f / 256.0f);
    mean.y *= (1.0f / 256.0f);
    float2 xm = make_float2(x.x - mean.x, x.y - mean.y);
    float2 var = half_sum2(make_float2(xm.x * xm.x, xm.y * xm.y), s_red2, tid);
    var.x *= (1.0f / 256.0f);
    var.y *= (1.0f / 256.0f);
    float gg = g[t], bbf = bb[t];
    return make_float2(xm.x / sqrtf(var.x + 1e-5f) * gg + bbf,
                       xm.y / sqrtf(var.y + 1e-5f) * gg + bbf);
}

// ---------------------------------------------------------------------------
// Megakernel: one block per 4 TOKENS (512 threads; half = token pair, each
// thread carries a float2 accumulator for its pair). Weight L2 traffic /4
// vs. one-token blocks; grid = 160 -> <=1 block/CU, no serialization tail.
struct MegaW {
    const float *traj, *noisy;
    const float *bvb, *bob, *bq, *bo;
    const float *n1g, *n1b, *n2g, *n2b;
    const float *fb1, *fb2, *n3g, *n3b;
    const float *cb1, *cl1g, *cl1b, *cb2, *cl2g, *cl2b, *cw3, *cb3;
    const float *rb1, *rb2, *rw3, *rb3;
};

__global__ __launch_bounds__(512, 2)
void mega_kernel(const float* __restrict__ gw, const float* __restrict__ wsumw,
                 const float* __restrict__ K1, const float* __restrict__ V1,
                 const float* __restrict__ u, const float* __restrict__ ss,
                 const uint2* __restrict__ bvwp, const uint2* __restrict__ bowp,
                 const uint2* __restrict__ wqp, const uint2* __restrict__ wop,
                 const uint2* __restrict__ fw1p, const uint2* __restrict__ fw2p,
                 const uint2* __restrict__ cw1p, const uint2* __restrict__ cw2p,
                 const uint2* __restrict__ rw1p, const uint2* __restrict__ rw2p,
                 MegaW W, float* __restrict__ out) {
    int blk = blockIdx.x;
    int tid = threadIdx.x;
    int half = tid >> 8;
    int t = tid & 255;
    int tok0 = blk * 4;                    // 4 | 20 -> group never crosses batch
    int tokA = tok0 + half * 2;
    int tokB = tokA + 1;
    int b = tok0 / NM;
    __shared__ __align__(16) float2 s_a2[2][ND];
    __shared__ __align__(16) float2 s_b2[2][ND];
    __shared__ __align__(16) float2 s_sc2[2][ND];
    __shared__ __align__(16) float2 s_h2[2][NFF];
    __shared__ float2 s_red2[8];

    // --- bev value GEMM: sampled' = gw @ W_v + b_v * wsum
    s_sc2[half][t] = make_float2(gw[(size_t)tokA * ND + t], gw[(size_t)tokB * ND + t]);
    float wsA = wsumw[tokA], wsB = wsumw[tokB];
    __syncthreads();
    float bvbt = W.bvb[t];
    float2 acc2 = gemm256x2(bvwp, s_sc2[half], t, make_float2(bvbt * wsA, bvbt * wsB));
    __syncthreads();
    s_b2[half][t] = acc2;
    __syncthreads();
    // --- bev out GEMM + residual with traj_feature -> t0 in s_a2
    float bobt = W.bob[t];
    acc2 = gemm256x2(bowp, s_b2[half], t,
                     make_float2(bobt + W.traj[(size_t)tokA * ND + t],
                                 bobt + W.traj[(size_t)tokB * ND + t]));
    s_a2[half][t] = acc2;
    __syncthreads();
    // --- agents attention: q projection
    float bqt = W.bq[t];
    acc2 = gemm256x2(wqp, s_a2[half], t, make_float2(bqt, bqt));
    __syncthreads();
    s_b2[half][t] = acc2;   // q (dual)
    __syncthreads();
    int h = t >> 5, kk = t & 31;
    {
        const float* Krow = K1 + ((size_t)(b * NA + kk)) * ND + h * 32;
        const float2* qrow = s_b2[half] + h * 32;
        float2 sc = make_float2(0.f, 0.f);
        for (int j = 0; j < 32; j++) sc = pk_fma(qrow[j], Krow[j], sc);
        s_sc2[half][t] = make_float2(sc.x * 0.17677669529663687f, sc.y * 0.17677669529663687f);
    }
    __syncthreads();
    // softmax over the 32 keys of this head (per token component)
    {
        const float2* scrow = s_sc2[half] + h * 32;
        float2 mx = make_float2(-1e30f, -1e30f);
        for (int j = 0; j < 32; j++) {
            mx.x = fmaxf(mx.x, scrow[j].x);
            mx.y = fmaxf(mx.y, scrow[j].y);
        }
        float2 den = make_float2(0.f, 0.f);
        for (int j = 0; j < 32; j++) {
            den.x += expf(scrow[j].x - mx.x);
            den.y += expf(scrow[j].y - mx.y);
        }
        float2 me = s_sc2[half][t];
        float2 p = make_float2(expf(me.x - mx.x) / den.x, expf(me.y - mx.y) / den.y);
        __syncthreads();
        s_sc2[half][t] = p;
        __syncthreads();
    }
    // attn out
    {
        const float* Vb = V1 + (size_t)b * NA * ND;
        const float2* prow = s_sc2[half] + h * 32;
        float2 o = make_float2(0.f, 0.f);
        for (int k = 0; k < 32; k++) o = pk_fma(prow[k], Vb[(size_t)k * ND + t], o);
        __syncthreads();
        s_b2[half][t] = o;
        __syncthreads();
    }
    // output proj + residual + LN1
    float bot = W.bo[t];
    acc2 = gemm256x2(wop, s_b2[half], t,
                     make_float2(bot + s_a2[half][t].x, bot + s_a2[half][t].y));
    float2 t1 = half_ln2(acc2, W.n1g, W.n1b, s_red2, tid);
    // ego (collapsed) residual + LN2  (u is per-batch, same for pair)
    float uu = u[(size_t)b * ND + t];
    float2 t2 = half_ln2(make_float2(t1.x + uu, t1.y + uu), W.n2g, W.n2b, s_red2, tid);
    __syncthreads();
    s_a2[half][t] = t2;
    __syncthreads();
    // --- FFN1: h = relu(t2 @ fw1 + fb1)  (K=256, N=1024, 4 outs/thread, dual)
    {
        float b0 = W.fb1[t], b1 = W.fb1[t + 256], b2 = W.fb1[t + 512], b3 = W.fb1[t + 768];
        float2 f0 = make_float2(b0, b0), f1 = make_float2(b1, b1);
        float2 f2 = make_float2(b2, b2), f3 = make_float2(b3, b3);
        const float4* a4 = (const float4*)s_a2[half];
        #pragma unroll 4
        for (int c4 = 0; c4 < 64; ++c4) {
            float4 p = a4[c4 * 2];
            float4 q = a4[c4 * 2 + 1];
            float2 a0 = make_float2(p.x, p.y), a1 = make_float2(p.z, p.w);
            float2 a2 = make_float2(q.x, q.y), a3 = make_float2(q.z, q.w);
            uint2 w; float w0, w1, w2, w3;
            w = fw1p[(c4 << 10) + t];
            dec2(w.x, w0, w1); dec2(w.y, w2, w3);
            f0 = pk_fma(a0, w0, f0); f0 = pk_fma(a1, w1, f0);
            f0 = pk_fma(a2, w2, f0); f0 = pk_fma(a3, w3, f0);
            w = fw1p[(c4 << 10) + 256 + t];
            dec2(w.x, w0, w1); dec2(w.y, w2, w3);
            f1 = pk_fma(a0, w0, f1); f1 = pk_fma(a1, w1, f1);
            f1 = pk_fma(a2, w2, f1); f1 = pk_fma(a3, w3, f1);
            w = fw1p[(c4 << 10) + 512 + t];
            dec2(w.x, w0, w1); dec2(w.y, w2, w3);
            f2 = pk_fma(a0, w0, f2); f2 = pk_fma(a1, w1, f2);
            f2 = pk_fma(a2, w2, f2); f2 = pk_fma(a3, w3, f2);
            w = fw1p[(c4 << 10) + 768 + t];
            dec2(w.x, w0, w1); dec2(w.y, w2, w3);
            f3 = pk_fma(a0, w0, f3); f3 = pk_fma(a1, w1, f3);
            f3 = pk_fma(a2, w2, f3); f3 = pk_fma(a3, w3, f3);
        }
        s_h2[half][t]       = make_float2(fmaxf(f0.x, 0.f), fmaxf(f0.y, 0.f));
        s_h2[half][t + 256] = make_float2(fmaxf(f1.x, 0.f), fmaxf(f1.y, 0.f));
        s_h2[half][t + 512] = make_float2(fmaxf(f2.x, 0.f), fmaxf(f2.y, 0.f));
        s_h2[half][t + 768] = make_float2(fmaxf(f3.x, 0.f), fmaxf(f3.y, 0.f));
    }
    __syncthreads();
    // --- FFN2 (K=1024, dual)
    {
        float fb2t = W.fb2[t];
        acc2 = make_float2(fb2t, fb2t);
        const float4* h4 = (const float4*)s_h2[half];
        #pragma unroll 8
        for (int c4 = 0; c4 < 256; ++c4) {
            float4 p = h4[c4 * 2];
            float4 q = h4[c4 * 2 + 1];
            uint2 w = fw2p[(c4 << 8) + t];
            float w0, w1, w2, w3;
            dec2(w.x, w0, w1); dec2(w.y, w2, w3);
            acc2 = pk_fma(make_float2(p.x, p.y), w0, acc2);
            acc2 = pk_fma(make_float2(p.z, p.w), w1, acc2);
            acc2 = pk_fma(make_float2(q.x, q.y), w2, acc2);
            acc2 = pk_fma(make_float2(q.z, q.w), w3, acc2);
        }
    }
    float2 t3 = half_ln2(acc2, W.n3g, W.n3b, s_red2, tid);   // no residual, per reference
    // modulation (per-batch, same for pair)
    float sc1 = ss[(size_t)b * 2 * ND + t];
    float sh1 = ss[(size_t)b * 2 * ND + ND + t];
    float2 tt = make_float2(t3.x * (1.f + sc1) + sh1, t3.y * (1.f + sc1) + sh1);
    __syncthreads();
    s_a2[half][t] = tt;
    __syncthreads();
    // --- cls head
    float cb1t = W.cb1[t];
    acc2 = gemm256x2(cw1p, s_a2[half], t, make_float2(cb1t, cb1t));
    float2 h1 = half_ln2(make_float2(fmaxf(acc2.x, 0.f), fmaxf(acc2.y, 0.f)),
                         W.cl1g, W.cl1b, s_red2, tid);
    __syncthreads();
    s_b2[half][t] = h1;
    __syncthreads();
    float cb2t = W.cb2[t];
    acc2 = gemm256x2(cw2p, s_b2[half], t, make_float2(cb2t, cb2t));
    float2 h2v = half_ln2(make_float2(fmaxf(acc2.x, 0.f), fmaxf(acc2.y, 0.f)),
                          W.cl2g, W.cl2b, s_red2, tid);
    float cw3t = W.cw3[t];
    float2 pc = half_sum2(make_float2(h2v.x * cw3t, h2v.y * cw3t), s_red2, tid);
    if (t == 0) {
        out[(size_t)NB * NM * NP * 3 + tokA] = pc.x + W.cb3[0];
        out[(size_t)NB * NM * NP * 3 + tokB] = pc.y + W.cb3[0];
    }
    // --- reg head
    float rb1t = W.rb1[t];
    acc2 = gemm256x2(rw1p, s_a2[half], t, make_float2(rb1t, rb1t));
    __syncthreads();
    s_b2[half][t] = make_float2(fmaxf(acc2.x, 0.f), fmaxf(acc2.y, 0.f));
    __syncthreads();
    float rb2t = W.rb2[t];
    acc2 = gemm256x2(rw2p, s_b2[half], t, make_float2(rb2t, rb2t));
    __syncthreads();
    s_b2[half][t] = make_float2(fmaxf(acc2.x, 0.f), fmaxf(acc2.y, 0.f));
    __syncthreads();
    if (t < 24) {
        float rb3t = W.rb3[t];
        float2 r3 = make_float2(rb3t, rb3t);
        const float2* sb = s_b2[half];
        for (int c = 0; c < ND; c++) r3 = pk_fma(sb[c], W.rw3[c * 24 + t], r3);
        int ts = t / 3, k2 = t % 3;
        if (k2 < 2) {
            out[((size_t)tokA * NP + ts) * 3 + k2] = r3.x + W.noisy[((size_t)tokA * NP + ts) * 2 + k2];
            out[((size_t)tokB * NP + ts) * 3 + k2] = r3.y + W.noisy[((size_t)tokB * NP + ts) * 2 + k2];
        } else {
            out[((size_t)tokA * NP + ts) * 3 + k2] = tanhf(r3.x) * 3.14159265358979323846f;
            out[((size_t)tokB * NP + ts) * 3 + k2] = tanhf(r3.y) * 3.14159265358979323846f;
        }
    }
}

// ---------------------------------------------------------------------------
extern "C" void kernel_launch(void* const* d_in, const int* in_sizes, int n_in,
                              void* d_out, int out_size, void* d_ws, size_t ws_size,
                              hipStream_t stream) {
    const float* traj   = (const float*)d_in[0];
    const float* noisy  = (const float*)d_in[1];
    const float* bev    = (const float*)d_in[2];
    const float* agents = (const float*)d_in[3];
    const float* ego    = (const float*)d_in[4];
    const float* temb   = (const float*)d_in[5];
    const float* bvw = (const float*)d_in[7];
    const float* bvb = (const float*)d_in[8];
    const float* baw = (const float*)d_in[9];
    const float* bab = (const float*)d_in[10];
    const float* bow = (const float*)d_in[11];
    const float* bob = (const float*)d_in[12];
    const float* aq_wq = (const float*)d_in[13];
    const float* aq_bq = (const float*)d_in[14];
    const float* aq_wk = (const float*)d_in[15];
    const float* aq_bk = (const float*)d_in[16];
    const float* aq_wv = (const float*)d_in[17];
    const float* aq_bv = (const float*)d_in[18];
    const float* aq_wo = (const float*)d_in[19];
    const float* aq_bo = (const float*)d_in[20];
    // 21..24: eq_wq/bq/wk/bk dead (Lk==1 -> softmax==1)
    const float* eq_wv = (const float*)d_in[25];
    const float* eq_bv = (const float*)d_in[26];
    const float* eq_wo = (const float*)d_in[27];
    const float* eq_bo = (const float*)d_in[28];
    const float* fw1 = (const float*)d_in[29];
    const float* fb1 = (const float*)d_in[30];
    const float* fw2 = (const float*)d_in[31];
    const float* fb2 = (const float*)d_in[32];
    const float* n1g = (const float*)d_in[33];
    const float* n1b = (const float*)d_in[34];
    const float* n2g = (const float*)d_in[35];
    const float* n2b = (const float*)d_in[36];
    const float* n3g = (const float*)d_in[37];
    const float* n3b = (const float*)d_in[38];
    const float* modw = (const float*)d_in[39];
    const float* modb = (const float*)d_in[40];
    const float* cw1 = (const float*)d_in[41];
    const float* cb1 = (const float*)d_in[42];
    const float* cl1g = (const float*)d_in[43];
    const float* cl1b = (const float*)d_in[44];
    const float* cw2 = (const float*)d_in[45];
    const float* cb2 = (const float*)d_in[46];
    const float* cl2g = (const float*)d_in[47];
    const float* cl2b = (const float*)d_in[48];
    const float* cw3 = (const float*)d_in[49];
    const float* cb3 = (const float*)d_in[50];
    const float* rw1 = (const float*)d_in[51];
    const float* rb1 = (const float*)d_in[52];
    const float* rw2 = (const float*)d_in[53];
    const float* rb2 = (const float*)d_in[54];
    const float* rw3 = (const float*)d_in[55];
    const float* rb3 = (const float*)d_in[56];

    float* ws = (float*)d_ws;
    float* gw    = ws + WS_GW;
    float* wsumw = ws + WS_WSUM;
    float* K1    = ws + WS_K1;
    float* V1    = ws + WS_V1;
    float* u     = ws + WS_U;
    float* ssb   = ws + WS_SS;
    unsigned short* pk = (unsigned short*)(ws + WS_PACK);

    // ---- fused prologue: pack + gather + kv + perb in one dispatch
    PackArgs pa;
    const float* srcs[10] = {bvw, bow, aq_wq, aq_wo, cw1, cw2, rw1, rw2, fw1, fw2};
    int lg[10]  = {8, 8, 8, 8, 8, 8, 8, 8, 10, 8};
    int el[10]  = {65536, 65536, 65536, 65536, 65536, 65536, 65536, 65536, 262144, 262144};
    int off[10] = {PK_BVW, PK_BOW, PK_WQ, PK_WO, PK_CW1, PK_CW2, PK_RW1, PK_RW2, PK_FW1, PK_FW2};
    for (int i = 0; i < 10; i++) { pa.src[i] = srcs[i]; pa.log2N[i] = lg[i]; pa.elems[i] = el[i]; pa.dstoff[i] = off[i]; }

    ProArgs PA;
    PA.traj = traj; PA.noisy = noisy; PA.bev = bev; PA.attn_w = baw; PA.attn_b = bab;
    PA.agents = agents; PA.wk = aq_wk; PA.bk = aq_bk; PA.wv = aq_wv; PA.bv = aq_bv;
    PA.ego = ego; PA.eq_wv = eq_wv; PA.eq_bv = eq_bv; PA.eq_wo = eq_wo; PA.eq_bo = eq_bo;
    PA.temb = temb; PA.modw = modw; PA.modb = modb;
    PA.gw = gw; PA.wsum = wsumw; PA.K1 = K1; PA.V1 = V1; PA.u = u; PA.ss = ssb;
    PA.pk = pk;

    prologue_kernel<<<dim3(PRO_GRID), dim3(256), 0, stream>>>(PA, pa);

    MegaW W;
    W.traj = traj; W.noisy = noisy;
    W.bvb = bvb; W.bob = bob; W.bq = aq_bq; W.bo = aq_bo;
    W.n1g = n1g; W.n1b = n1b; W.n2g = n2g; W.n2b = n2b;
    W.fb1 = fb1; W.fb2 = fb2; W.n3g = n3g; W.n3b = n3b;
    W.cb1 = cb1; W.cl1g = cl1g; W.cl1b = cl1b;
    W.cb2 = cb2; W.cl2g = cl2g; W.cl2b = cl2b; W.cw3 = cw3; W.cb3 = cb3;
    W.rb1 = rb1; W.rb2 = rb2; W.rw3 = rw3; W.rb3 = rb3;

    mega_kernel<<<dim3(NB * NM / 4), dim3(512), 0, stream>>>(gw, wsumw, K1, V1, u, ssb,
        (const uint2*)(pk + PK_BVW), (const uint2*)(pk + PK_BOW),
        (const uint2*)(pk + PK_WQ),  (const uint2*)(pk + PK_WO),
        (const uint2*)(pk + PK_FW1), (const uint2*)(pk + PK_FW2),
        (const uint2*)(pk + PK_CW1), (const uint2*)(pk + PK_CW2),
        (const uint2*)(pk + PK_RW1), (const uint2*)(pk + PK_RW2),
        W, (float*)d_out);
}